// Round 15
// baseline (161.047 us; speedup 1.0000x reference)
//
#include <hip/hip_runtime.h>
#include <hip/hip_bf16.h>

#define NB 16
#define C 256
#define C4 64
#define HDIM 128
#define WDIM 128
#define HW 16384

typedef __bf16 bf16x8 __attribute__((ext_vector_type(8)));
typedef float f32x4 __attribute__((ext_vector_type(4)));

__device__ __forceinline__ unsigned short f2bf(float x) {
    union { __bf16 h; unsigned short u; } c;
    c.h = (__bf16)x;                       // RNE
    return c.u;
}
__device__ __forceinline__ float bf2f(unsigned short b) {
    union { float f; unsigned u; } a; a.u = ((unsigned)b) << 16; return a.f;
}

// ---------------------------------------------------------------------------
// K0: pack conv_w (64x256) and fuse_w (256x64) into MFMA fragment order,
// compute fuse_b_eff[c] = fuse_b[c] + sum_o fuse_w[c][o]*dw_b[o].
// Fragment (16x16x32): lane = (i&15) | (((k>>3)&3)<<4), e = k&7. The same
// packed data serves as A-frag of W and B-frag of W^T (layouts are
// transpose-symmetric), which is what lets K1/K3 swap mfma operands freely.
// ---------------------------------------------------------------------------
__global__ __launch_bounds__(256) void k0_pack(
    const float* __restrict__ conv_w, const float* __restrict__ fuse_w,
    const float* __restrict__ fuse_b, const float* __restrict__ dw_b,
    unsigned short* __restrict__ cwpk, unsigned short* __restrict__ fwpk,
    float* __restrict__ fbe)
{
    int tid = blockIdx.x * 256 + threadIdx.x;   // 0..16383
    {   // conv_w: M=64, K=256
        int m = tid >> 8, k = tid & 255;
        int frag = (m >> 4) * 8 + (k >> 5);
        int lane = (m & 15) | (((k >> 3) & 3) << 4);
        int e = k & 7;
        cwpk[(frag * 64 + lane) * 8 + e] = f2bf(conv_w[m * 256 + k]);
    }
    {   // fuse_w: M=256, K=64
        int m = tid >> 6, k = tid & 63;
        int frag = (m >> 4) * 2 + (k >> 5);
        int lane = (m & 15) | (((k >> 3) & 3) << 4);
        int e = k & 7;
        fwpk[(frag * 64 + lane) * 8 + e] = f2bf(fuse_w[m * 64 + k]);
    }
    if (tid < 256) {
        float s = fuse_b[tid];
        #pragma unroll
        for (int o = 0; o < 64; ++o) s += fuse_w[tid * 64 + o] * dw_b[o];
        fbe[tid] = s;
    }
}

// ---------------------------------------------------------------------------
// K1: f = conv1(x) + conv_b  (GEMM, operand-swapped: D^T = x^T . conv_w^T).
// TWO-ROW blocks: 1024 blocks x 512 thr; each channel's x-read is one 1 KB
// run (one full wave-load). Ping-pong LDS, issue-early prefetch, ONE
// barrier/chunk. R15 A/B: x loads are PLAIN (R1-R14 used nontemporal, never
// isolated; nt bypasses L2 allocation and may demote HBM scheduling --
// suspected cause of the ~4.4 TB/s read plateau vs 6.3 TB/s copy ceiling).
// ---------------------------------------------------------------------------
__global__ __launch_bounds__(512) void k1_conv(
    const float* __restrict__ x, const unsigned short* __restrict__ cwpk,
    const float* __restrict__ conv_b, unsigned short* __restrict__ f_ws,
    float* __restrict__ psum)
{
    __shared__ __align__(16) unsigned short xlds[2][32 * 258];  // 2 x 16512 B
    int blk = blockIdx.x;                         // 1024 = 16 n * 64 hpair
    int n = blk >> 6;
    int h0 = (blk & 63) * 2;
    int p0 = h0 * WDIM;                           // 256 px = two rows
    int t = threadIdx.x;
    int lane = t & 63, wv = t >> 6, gq = lane >> 4, l15 = lane & 15;
    const float* xn = x + (size_t)n * C * HW + p0;

    int lpx = (t & 63) * 4;                       // 0..252: pixel base (f32x4)
    // staging: wave wv loads channels {j*8 + wv}, each 64 lanes x 16 B = 1 KB

    f32x4 r[4];
    #pragma unroll
    for (int j = 0; j < 4; ++j)
        r[j] = *reinterpret_cast<const f32x4*>(&xn[(size_t)(j * 8 + wv) * HW + lpx]);

    f32x4 acc[2][4];
    #pragma unroll
    for (int pt = 0; pt < 2; ++pt)
        #pragma unroll
        for (int m = 0; m < 4; ++m) acc[pt][m] = (f32x4){0.f, 0.f, 0.f, 0.f};

    for (int kc = 0; kc < 8; ++kc) {
        unsigned short* buf = xlds[kc & 1];
        unsigned int pk[4][2];
        #pragma unroll
        for (int j = 0; j < 4; ++j) {
            pk[j][0] = ((unsigned)f2bf(r[j].y) << 16) | f2bf(r[j].x);
            pk[j][1] = ((unsigned)f2bf(r[j].w) << 16) | f2bf(r[j].z);
        }
        if (kc < 7) {                  // issue-early: loads fly under barrier+MFMA
            #pragma unroll
            for (int j = 0; j < 4; ++j)
                r[j] = *reinterpret_cast<const f32x4*>(
                    &xn[(size_t)((kc + 1) * 32 + j * 8 + wv) * HW + lpx]);
        }
        #pragma unroll
        for (int j = 0; j < 4; ++j) {
            unsigned int* dst = reinterpret_cast<unsigned int*>(
                &buf[(j * 8 + wv) * 258 + lpx]);
            dst[0] = pk[j][0];
            dst[1] = pk[j][1];
        }
        __syncthreads();                          // tile visible; prev buf free
        bf16x8 a[4];
        #pragma unroll
        for (int m = 0; m < 4; ++m)
            a[m] = *reinterpret_cast<const bf16x8*>(cwpk + ((m * 8 + kc) * 64 + lane) * 8);
        #pragma unroll
        for (int pt = 0; pt < 2; ++pt) {
            int px = wv * 32 + pt * 16 + l15;
            union { bf16x8 v; unsigned short u[8]; } b;
            #pragma unroll
            for (int e = 0; e < 8; ++e)
                b.u[e] = buf[(gq * 8 + e) * 258 + px];
            #pragma unroll
            for (int m = 0; m < 4; ++m)           // SWAPPED: D^T = x^T . w^T
                acc[pt][m] = __builtin_amdgcn_mfma_f32_16x16x32_bf16(b.v, a[m], acc[pt][m], 0, 0, 0);
        }
    }

    // lane holds: o = m*16 + l15, px = wv*32 + pt*16 + gq*4 + e  (row = px>>7)
    float cbv[4];
    #pragma unroll
    for (int m = 0; m < 4; ++m) cbv[m] = conv_b[m * 16 + l15];

    float cs[4][3];
    #pragma unroll
    for (int m = 0; m < 4; ++m) cs[m][0] = cs[m][1] = cs[m][2] = 0.f;

    unsigned short* fn = f_ws + (size_t)n * C4 * HW;
    #pragma unroll
    for (int pt = 0; pt < 2; ++pt) {
        int pxb = wv * 32 + pt * 16 + gq * 4;     // 0..255 within the 2 rows
        int cl = pxb & 127;                       // column within its row
        #pragma unroll
        for (int m = 0; m < 4; ++m) {
            int o = m * 16 + l15;
            union { unsigned int d[2]; unsigned short u[4]; } pk2;
            #pragma unroll
            for (int e = 0; e < 4; ++e) {
                float v = acc[pt][m][e] + cbv[m];
                pk2.u[e] = f2bf(v);
                int col = cl + e;
                if (col < 43)               cs[m][0] += v;
                if (col >= 42 && col < 86)  cs[m][1] += v;
                if (col >= 85)              cs[m][2] += v;
            }
            *reinterpret_cast<uint2*>(&fn[(size_t)o * HW + p0 + pxb]) =
                (uint2){pk2.d[0], pk2.d[1]};
        }
    }

    // reduce col-bin sums over the 4 gq groups (lanes differ in bits 4-5);
    // each wave is entirely within one row: waves 0-3 = row h0, 4-7 = h0+1
    #pragma unroll
    for (int m = 0; m < 4; ++m)
        #pragma unroll
        for (int b = 0; b < 3; ++b) {
            float v = cs[m][b];
            v += __shfl_xor(v, 16, 64);
            v += __shfl_xor(v, 32, 64);
            cs[m][b] = v;
        }

    __syncthreads();                    // all staging reads done -> alias OK
    float (*xpool)[192] = reinterpret_cast<float(*)[192]>(&xlds[0][0]);
    if (gq == 0) {
        #pragma unroll
        for (int m = 0; m < 4; ++m)
            #pragma unroll
            for (int b = 0; b < 3; ++b)
                xpool[wv][(m * 16 + l15) * 3 + b] = cs[m][b];
    }
    __syncthreads();
    if (t < 192) {
        psum[(size_t)(n * 128 + h0) * 192 + t] =
            xpool[0][t] + xpool[1][t] + xpool[2][t] + xpool[3][t];
    } else if (t >= 256 && t < 448) {
        int tt = t - 256;
        psum[(size_t)(n * 128 + h0 + 1) * 192 + tt] =
            xpool[4][tt] + xpool[5][tt] + xpool[6][tt] + xpool[7][tt];
    }
}

// ---------------------------------------------------------------------------
// K2r: gsum[n,o,i,j] = sum over h (with torch-adaptive h-bin overlap: rows
// 42 & 85 belong to two bins) of psum[n*128+h][o*3+b].
// 1024 blocks (one per (n,o)) x 128 threads (one per h).
// ---------------------------------------------------------------------------
__global__ __launch_bounds__(128) void k2_reduce(
    const float* __restrict__ psum, float* __restrict__ gsum)
{
    int bid = blockIdx.x;               // 1024
    int n = bid >> 6, o = bid & 63;
    int h = threadIdx.x;                // 0..127
    const float* ps = psum + ((size_t)(n * 128 + h)) * 192 + o * 3;
    float v0 = ps[0], v1 = ps[1], v2 = ps[2];

    float s[9];
    #pragma unroll
    for (int k = 0; k < 9; ++k) s[k] = 0.f;
    if (h < 43)            { s[0] += v0; s[1] += v1; s[2] += v2; }
    if (h >= 42 && h < 86) { s[3] += v0; s[4] += v1; s[5] += v2; }
    if (h >= 85)           { s[6] += v0; s[7] += v1; s[8] += v2; }

    int lane = h & 63, wid = h >> 6;
    #pragma unroll
    for (int k = 0; k < 9; ++k) {
        float v = s[k];
        for (int off = 32; off > 0; off >>= 1) v += __shfl_down(v, off, 64);
        s[k] = v;
    }
    __shared__ float red[2][9];
    if (lane == 0) {
        #pragma unroll
        for (int k = 0; k < 9; ++k) red[wid][k] = s[k];
    }
    __syncthreads();
    if (threadIdx.x < 9)
        gsum[(n * 64 + o) * 9 + threadIdx.x] = red[0][threadIdx.x] + red[1][threadIdx.x];
}

// ---------------------------------------------------------------------------
// K3: y = depthwise3x3(f, g) ; out = fuse_w . y + fuse_b_eff
// Block: one (n, row h), full 128 cols, 512 threads (8 waves).
// MFMA operand-swapped: D^T = y^T . fuse_w^T -> f32x4 out-stores.
// ---------------------------------------------------------------------------
__global__ __launch_bounds__(512) void k3_dwfuse(
    const unsigned short* __restrict__ f_ws, const float* __restrict__ gsum,
    const unsigned short* __restrict__ fwpk, const float* __restrict__ fbe,
    float* __restrict__ out)
{
    __shared__ unsigned short ylds[64][136];
    int blk = blockIdx.x;                 // 2048
    int n = blk >> 7;
    int h = blk & 127;
    int t = threadIdx.x;

    {   // depthwise: thread t -> channel o = t>>3, strip q = t&7 (16 px)
        const float ginv[9] = {
            1.f/1849.f, 1.f/1892.f, 1.f/1849.f,
            1.f/1892.f, 1.f/1936.f, 1.f/1892.f,
            1.f/1849.f, 1.f/1892.f, 1.f/1849.f };
        int o = t >> 3, q = t & 7;
        int wb = q * 16;
        const unsigned short* fp = f_ws + (size_t)(n * 64 + o) * HW;
        const float* gp = gsum + (n * 64 + o) * 9;
        float gv[9];
        #pragma unroll
        for (int k = 0; k < 9; ++k) gv[k] = gp[k] * ginv[k];
        float y[16];
        #pragma unroll
        for (int i = 0; i < 16; ++i) y[i] = 0.f;
        #pragma unroll
        for (int dy = -1; dy <= 1; ++dy) {
            int hh = h + dy;
            if (hh < 0 || hh >= HDIM) continue;
            const unsigned short* row = fp + hh * WDIM;
            union { uint4 q4; unsigned short u[8]; } bA, bB;
            bA.q4 = *reinterpret_cast<const uint4*>(row + wb);
            bB.q4 = *reinterpret_cast<const uint4*>(row + wb + 8);
            float lft = bf2f(row[wb == 0 ? 0 : wb - 1]);
            if (wb == 0)   lft = 0.f;
            float rgt = bf2f(row[wb == 112 ? 127 : wb + 16]);
            if (wb == 112) rgt = 0.f;
            float rv[18];
            rv[0] = lft;
            #pragma unroll
            for (int z = 0; z < 8; ++z) rv[1 + z] = bf2f(bA.u[z]);
            #pragma unroll
            for (int z = 0; z < 8; ++z) rv[9 + z] = bf2f(bB.u[z]);
            rv[17] = rgt;
            float g0 = gv[(dy + 1) * 3], g1 = gv[(dy + 1) * 3 + 1], g2 = gv[(dy + 1) * 3 + 2];
            #pragma unroll
            for (int i = 0; i < 16; ++i)
                y[i] += g0 * rv[i] + g1 * rv[i + 1] + g2 * rv[i + 2];
        }
        union { uint4 q4[2]; unsigned short u[16]; } pk;
        #pragma unroll
        for (int i = 0; i < 16; ++i) pk.u[i] = f2bf(y[i]);
        *reinterpret_cast<uint4*>(&ylds[o][wb])     = pk.q4[0];
        *reinterpret_cast<uint4*>(&ylds[o][wb + 8]) = pk.q4[1];
    }
    __syncthreads();

    int lane = t & 63, wv = t >> 6, gq = lane >> 4, l15 = lane & 15;
    int chb = (wv & 3) * 64, pxb = (wv >> 2) * 64;
    f32x4 acc[4][4];
    #pragma unroll
    for (int a = 0; a < 4; ++a)
        #pragma unroll
        for (int b = 0; b < 4; ++b) acc[a][b] = (f32x4){0.f,0.f,0.f,0.f};

    #pragma unroll
    for (int kc = 0; kc < 2; ++kc) {
        bf16x8 bfr[4];
        #pragma unroll
        for (int pj = 0; pj < 4; ++pj) {
            union { bf16x8 v; unsigned short u[8]; } bb;
            #pragma unroll
            for (int e = 0; e < 8; ++e)
                bb.u[e] = ylds[kc * 32 + gq * 8 + e][pxb + pj * 16 + l15];
            bfr[pj] = bb.v;
        }
        #pragma unroll
        for (int mc = 0; mc < 4; ++mc) {
            int mtile = (wv & 3) * 4 + mc;
            bf16x8 a = *reinterpret_cast<const bf16x8*>(
                fwpk + ((mtile * 2 + kc) * 64 + lane) * 8);
            #pragma unroll
            for (int pj = 0; pj < 4; ++pj)        // SWAPPED: D^T = y^T . w^T
                acc[mc][pj] = __builtin_amdgcn_mfma_f32_16x16x32_bf16(bfr[pj], a, acc[mc][pj], 0, 0, 0);
        }
    }

    // lane holds: c = chb + mc*16 + l15, px = pxb + pj*16 + gq*4 + e
    size_t outbase = (size_t)n * C * HW + (size_t)h * WDIM;
    #pragma unroll
    for (int mc = 0; mc < 4; ++mc) {
        int c = chb + mc * 16 + l15;
        float bias = fbe[c];
        #pragma unroll
        for (int pj = 0; pj < 4; ++pj) {
            int w = pxb + pj * 16 + gq * 4;
            f32x4 vv;
            #pragma unroll
            for (int e = 0; e < 4; ++e) vv[e] = acc[mc][pj][e] + bias;
            *reinterpret_cast<f32x4*>(&out[outbase + (size_t)c * HW + w]) = vv;
        }
    }
}

// ---------------------------------------------------------------------------
extern "C" void kernel_launch(void* const* d_in, const int* in_sizes, int n_in,
                              void* d_out, int out_size, void* d_ws, size_t ws_size,
                              hipStream_t stream) {
    const float* x      = (const float*)d_in[0];
    const float* conv_w = (const float*)d_in[1];
    const float* conv_b = (const float*)d_in[2];
    const float* dw_b   = (const float*)d_in[3];
    const float* fuse_w = (const float*)d_in[4];
    const float* fuse_b = (const float*)d_in[5];
    float* out = (float*)d_out;

    char* ws = (char*)d_ws;
    unsigned short* f_ws = (unsigned short*)ws;                      // 32 MiB
    float* psum          = (float*)(ws + 33554432);                  // 1.57 MiB
    float* gsum          = (float*)(ws + 33554432 + 2097152);        // 36 KiB
    unsigned short* cwpk = (unsigned short*)(ws + 33554432 + 2097152 + 36864);
    unsigned short* fwpk = (unsigned short*)(ws + 33554432 + 2097152 + 36864 + 32768);
    float* fbe           = (float*)(ws + 33554432 + 2097152 + 36864 + 32768 + 32768);

    k0_pack<<<dim3(64), dim3(256), 0, stream>>>(conv_w, fuse_w, fuse_b, dw_b, cwpk, fwpk, fbe);
    k1_conv<<<dim3(1024), dim3(512), 0, stream>>>(x, cwpk, conv_b, f_ws, psum);
    k2_reduce<<<dim3(1024), dim3(128), 0, stream>>>(psum, gsum);
    k3_dwfuse<<<dim3(2048), dim3(512), 0, stream>>>(f_ws, gsum, fwpk, fbe, out);
}

// Round 16
// 155.290 us; speedup vs baseline: 1.0371x; 1.0371x over previous
//
#include <hip/hip_runtime.h>
#include <hip/hip_bf16.h>

#define NB 16
#define C 256
#define C4 64
#define HDIM 128
#define WDIM 128
#define HW 16384

typedef __bf16 bf16x8 __attribute__((ext_vector_type(8)));
typedef float f32x4 __attribute__((ext_vector_type(4)));

__device__ __forceinline__ unsigned short f2bf(float x) {
    union { __bf16 h; unsigned short u; } c;
    c.h = (__bf16)x;                       // RNE
    return c.u;
}
__device__ __forceinline__ float bf2f(unsigned short b) {
    union { float f; unsigned u; } a; a.u = ((unsigned)b) << 16; return a.f;
}

// ---------------------------------------------------------------------------
// Cache policy (established by A/B over R14-R16):
//  - x loads:  NONTEMPORAL. R15 proved plain loads cost +22 us: the 268 MB
//    x stream evicts f (32 MB) from LLC, pushing k3's 96 MB f re-reads to HBM.
//  - f loads/stores: plain (f must stay LLC-resident between k1 and k3).
//  - out stores: NONTEMPORAL (R16 isolated test): out is write-once,
//    never re-read; plain stores allocate 268 MB in LLC during k3 and evict
//    f between its 1st and 3rd read. Same pollution mechanism as x.
// ---------------------------------------------------------------------------

// ---------------------------------------------------------------------------
// K0: pack conv_w (64x256) and fuse_w (256x64) into MFMA fragment order,
// compute fuse_b_eff[c] = fuse_b[c] + sum_o fuse_w[c][o]*dw_b[o].
// Fragment (16x16x32): lane = (i&15) | (((k>>3)&3)<<4), e = k&7. The same
// packed data serves as A-frag of W and B-frag of W^T (layouts are
// transpose-symmetric), which is what lets K1/K3 swap mfma operands freely.
// ---------------------------------------------------------------------------
__global__ __launch_bounds__(256) void k0_pack(
    const float* __restrict__ conv_w, const float* __restrict__ fuse_w,
    const float* __restrict__ fuse_b, const float* __restrict__ dw_b,
    unsigned short* __restrict__ cwpk, unsigned short* __restrict__ fwpk,
    float* __restrict__ fbe)
{
    int tid = blockIdx.x * 256 + threadIdx.x;   // 0..16383
    {   // conv_w: M=64, K=256
        int m = tid >> 8, k = tid & 255;
        int frag = (m >> 4) * 8 + (k >> 5);
        int lane = (m & 15) | (((k >> 3) & 3) << 4);
        int e = k & 7;
        cwpk[(frag * 64 + lane) * 8 + e] = f2bf(conv_w[m * 256 + k]);
    }
    {   // fuse_w: M=256, K=64
        int m = tid >> 6, k = tid & 63;
        int frag = (m >> 4) * 2 + (k >> 5);
        int lane = (m & 15) | (((k >> 3) & 3) << 4);
        int e = k & 7;
        fwpk[(frag * 64 + lane) * 8 + e] = f2bf(fuse_w[m * 64 + k]);
    }
    if (tid < 256) {
        float s = fuse_b[tid];
        #pragma unroll
        for (int o = 0; o < 64; ++o) s += fuse_w[tid * 64 + o] * dw_b[o];
        fbe[tid] = s;
    }
}

// ---------------------------------------------------------------------------
// K1: f = conv1(x) + conv_b  (GEMM, operand-swapped: D^T = x^T . conv_w^T).
// TWO-ROW blocks: 1024 blocks x 512 thr; each channel's x-read is one 1 KB
// run (one full wave-load, nontemporal). Ping-pong LDS, issue-early
// prefetch, ONE barrier/chunk. Pool partials per h-row; xpool aliases the
// staging buffer after the final barrier.
// ---------------------------------------------------------------------------
__global__ __launch_bounds__(512) void k1_conv(
    const float* __restrict__ x, const unsigned short* __restrict__ cwpk,
    const float* __restrict__ conv_b, unsigned short* __restrict__ f_ws,
    float* __restrict__ psum)
{
    __shared__ __align__(16) unsigned short xlds[2][32 * 258];  // 2 x 16512 B
    int blk = blockIdx.x;                         // 1024 = 16 n * 64 hpair
    int n = blk >> 6;
    int h0 = (blk & 63) * 2;
    int p0 = h0 * WDIM;                           // 256 px = two rows
    int t = threadIdx.x;
    int lane = t & 63, wv = t >> 6, gq = lane >> 4, l15 = lane & 15;
    const float* xn = x + (size_t)n * C * HW + p0;

    int lpx = (t & 63) * 4;                       // 0..252: pixel base (f32x4)
    // staging: wave wv loads channels {j*8 + wv}, each 64 lanes x 16 B = 1 KB

    f32x4 r[4];
    #pragma unroll
    for (int j = 0; j < 4; ++j)
        r[j] = __builtin_nontemporal_load(
            reinterpret_cast<const f32x4*>(&xn[(size_t)(j * 8 + wv) * HW + lpx]));

    f32x4 acc[2][4];
    #pragma unroll
    for (int pt = 0; pt < 2; ++pt)
        #pragma unroll
        for (int m = 0; m < 4; ++m) acc[pt][m] = (f32x4){0.f, 0.f, 0.f, 0.f};

    for (int kc = 0; kc < 8; ++kc) {
        unsigned short* buf = xlds[kc & 1];
        unsigned int pk[4][2];
        #pragma unroll
        for (int j = 0; j < 4; ++j) {
            pk[j][0] = ((unsigned)f2bf(r[j].y) << 16) | f2bf(r[j].x);
            pk[j][1] = ((unsigned)f2bf(r[j].w) << 16) | f2bf(r[j].z);
        }
        if (kc < 7) {                  // issue-early: loads fly under barrier+MFMA
            #pragma unroll
            for (int j = 0; j < 4; ++j)
                r[j] = __builtin_nontemporal_load(
                    reinterpret_cast<const f32x4*>(
                        &xn[(size_t)((kc + 1) * 32 + j * 8 + wv) * HW + lpx]));
        }
        #pragma unroll
        for (int j = 0; j < 4; ++j) {
            unsigned int* dst = reinterpret_cast<unsigned int*>(
                &buf[(j * 8 + wv) * 258 + lpx]);
            dst[0] = pk[j][0];
            dst[1] = pk[j][1];
        }
        __syncthreads();                          // tile visible; prev buf free
        bf16x8 a[4];
        #pragma unroll
        for (int m = 0; m < 4; ++m)
            a[m] = *reinterpret_cast<const bf16x8*>(cwpk + ((m * 8 + kc) * 64 + lane) * 8);
        #pragma unroll
        for (int pt = 0; pt < 2; ++pt) {
            int px = wv * 32 + pt * 16 + l15;
            union { bf16x8 v; unsigned short u[8]; } b;
            #pragma unroll
            for (int e = 0; e < 8; ++e)
                b.u[e] = buf[(gq * 8 + e) * 258 + px];
            #pragma unroll
            for (int m = 0; m < 4; ++m)           // SWAPPED: D^T = x^T . w^T
                acc[pt][m] = __builtin_amdgcn_mfma_f32_16x16x32_bf16(b.v, a[m], acc[pt][m], 0, 0, 0);
        }
    }

    // lane holds: o = m*16 + l15, px = wv*32 + pt*16 + gq*4 + e  (row = px>>7)
    float cbv[4];
    #pragma unroll
    for (int m = 0; m < 4; ++m) cbv[m] = conv_b[m * 16 + l15];

    float cs[4][3];
    #pragma unroll
    for (int m = 0; m < 4; ++m) cs[m][0] = cs[m][1] = cs[m][2] = 0.f;

    unsigned short* fn = f_ws + (size_t)n * C4 * HW;
    #pragma unroll
    for (int pt = 0; pt < 2; ++pt) {
        int pxb = wv * 32 + pt * 16 + gq * 4;     // 0..255 within the 2 rows
        int cl = pxb & 127;                       // column within its row
        #pragma unroll
        for (int m = 0; m < 4; ++m) {
            int o = m * 16 + l15;
            union { unsigned int d[2]; unsigned short u[4]; } pk2;
            #pragma unroll
            for (int e = 0; e < 4; ++e) {
                float v = acc[pt][m][e] + cbv[m];
                pk2.u[e] = f2bf(v);
                int col = cl + e;
                if (col < 43)               cs[m][0] += v;
                if (col >= 42 && col < 86)  cs[m][1] += v;
                if (col >= 85)              cs[m][2] += v;
            }
            *reinterpret_cast<uint2*>(&fn[(size_t)o * HW + p0 + pxb]) =
                (uint2){pk2.d[0], pk2.d[1]};
        }
    }

    // reduce col-bin sums over the 4 gq groups (lanes differ in bits 4-5);
    // each wave is entirely within one row: waves 0-3 = row h0, 4-7 = h0+1
    #pragma unroll
    for (int m = 0; m < 4; ++m)
        #pragma unroll
        for (int b = 0; b < 3; ++b) {
            float v = cs[m][b];
            v += __shfl_xor(v, 16, 64);
            v += __shfl_xor(v, 32, 64);
            cs[m][b] = v;
        }

    __syncthreads();                    // all staging reads done -> alias OK
    float (*xpool)[192] = reinterpret_cast<float(*)[192]>(&xlds[0][0]);
    if (gq == 0) {
        #pragma unroll
        for (int m = 0; m < 4; ++m)
            #pragma unroll
            for (int b = 0; b < 3; ++b)
                xpool[wv][(m * 16 + l15) * 3 + b] = cs[m][b];
    }
    __syncthreads();
    if (t < 192) {
        psum[(size_t)(n * 128 + h0) * 192 + t] =
            xpool[0][t] + xpool[1][t] + xpool[2][t] + xpool[3][t];
    } else if (t >= 256 && t < 448) {
        int tt = t - 256;
        psum[(size_t)(n * 128 + h0 + 1) * 192 + tt] =
            xpool[4][tt] + xpool[5][tt] + xpool[6][tt] + xpool[7][tt];
    }
}

// ---------------------------------------------------------------------------
// K2r: gsum[n,o,i,j] = sum over h (with torch-adaptive h-bin overlap: rows
// 42 & 85 belong to two bins) of psum[n*128+h][o*3+b].
// 1024 blocks (one per (n,o)) x 128 threads (one per h).
// ---------------------------------------------------------------------------
__global__ __launch_bounds__(128) void k2_reduce(
    const float* __restrict__ psum, float* __restrict__ gsum)
{
    int bid = blockIdx.x;               // 1024
    int n = bid >> 6, o = bid & 63;
    int h = threadIdx.x;                // 0..127
    const float* ps = psum + ((size_t)(n * 128 + h)) * 192 + o * 3;
    float v0 = ps[0], v1 = ps[1], v2 = ps[2];

    float s[9];
    #pragma unroll
    for (int k = 0; k < 9; ++k) s[k] = 0.f;
    if (h < 43)            { s[0] += v0; s[1] += v1; s[2] += v2; }
    if (h >= 42 && h < 86) { s[3] += v0; s[4] += v1; s[5] += v2; }
    if (h >= 85)           { s[6] += v0; s[7] += v1; s[8] += v2; }

    int lane = h & 63, wid = h >> 6;
    #pragma unroll
    for (int k = 0; k < 9; ++k) {
        float v = s[k];
        for (int off = 32; off > 0; off >>= 1) v += __shfl_down(v, off, 64);
        s[k] = v;
    }
    __shared__ float red[2][9];
    if (lane == 0) {
        #pragma unroll
        for (int k = 0; k < 9; ++k) red[wid][k] = s[k];
    }
    __syncthreads();
    if (threadIdx.x < 9)
        gsum[(n * 64 + o) * 9 + threadIdx.x] = red[0][threadIdx.x] + red[1][threadIdx.x];
}

// ---------------------------------------------------------------------------
// K3: y = depthwise3x3(f, g) ; out = fuse_w . y + fuse_b_eff
// Block: one (n, row h), full 128 cols, 512 threads (8 waves).
// MFMA operand-swapped: D^T = y^T . fuse_w^T -> f32x4 NONTEMPORAL out-stores
// (out is write-once; keeping it out of LLC protects f's residency).
// ---------------------------------------------------------------------------
__global__ __launch_bounds__(512) void k3_dwfuse(
    const unsigned short* __restrict__ f_ws, const float* __restrict__ gsum,
    const unsigned short* __restrict__ fwpk, const float* __restrict__ fbe,
    float* __restrict__ out)
{
    __shared__ unsigned short ylds[64][136];
    int blk = blockIdx.x;                 // 2048
    int n = blk >> 7;
    int h = blk & 127;
    int t = threadIdx.x;

    {   // depthwise: thread t -> channel o = t>>3, strip q = t&7 (16 px)
        const float ginv[9] = {
            1.f/1849.f, 1.f/1892.f, 1.f/1849.f,
            1.f/1892.f, 1.f/1936.f, 1.f/1892.f,
            1.f/1849.f, 1.f/1892.f, 1.f/1849.f };
        int o = t >> 3, q = t & 7;
        int wb = q * 16;
        const unsigned short* fp = f_ws + (size_t)(n * 64 + o) * HW;
        const float* gp = gsum + (n * 64 + o) * 9;
        float gv[9];
        #pragma unroll
        for (int k = 0; k < 9; ++k) gv[k] = gp[k] * ginv[k];
        float y[16];
        #pragma unroll
        for (int i = 0; i < 16; ++i) y[i] = 0.f;
        #pragma unroll
        for (int dy = -1; dy <= 1; ++dy) {
            int hh = h + dy;
            if (hh < 0 || hh >= HDIM) continue;
            const unsigned short* row = fp + hh * WDIM;
            union { uint4 q4; unsigned short u[8]; } bA, bB;
            bA.q4 = *reinterpret_cast<const uint4*>(row + wb);
            bB.q4 = *reinterpret_cast<const uint4*>(row + wb + 8);
            float lft = bf2f(row[wb == 0 ? 0 : wb - 1]);
            if (wb == 0)   lft = 0.f;
            float rgt = bf2f(row[wb == 112 ? 127 : wb + 16]);
            if (wb == 112) rgt = 0.f;
            float rv[18];
            rv[0] = lft;
            #pragma unroll
            for (int z = 0; z < 8; ++z) rv[1 + z] = bf2f(bA.u[z]);
            #pragma unroll
            for (int z = 0; z < 8; ++z) rv[9 + z] = bf2f(bB.u[z]);
            rv[17] = rgt;
            float g0 = gv[(dy + 1) * 3], g1 = gv[(dy + 1) * 3 + 1], g2 = gv[(dy + 1) * 3 + 2];
            #pragma unroll
            for (int i = 0; i < 16; ++i)
                y[i] += g0 * rv[i] + g1 * rv[i + 1] + g2 * rv[i + 2];
        }
        union { uint4 q4[2]; unsigned short u[16]; } pk;
        #pragma unroll
        for (int i = 0; i < 16; ++i) pk.u[i] = f2bf(y[i]);
        *reinterpret_cast<uint4*>(&ylds[o][wb])     = pk.q4[0];
        *reinterpret_cast<uint4*>(&ylds[o][wb + 8]) = pk.q4[1];
    }
    __syncthreads();

    int lane = t & 63, wv = t >> 6, gq = lane >> 4, l15 = lane & 15;
    int chb = (wv & 3) * 64, pxb = (wv >> 2) * 64;
    f32x4 acc[4][4];
    #pragma unroll
    for (int a = 0; a < 4; ++a)
        #pragma unroll
        for (int b = 0; b < 4; ++b) acc[a][b] = (f32x4){0.f,0.f,0.f,0.f};

    #pragma unroll
    for (int kc = 0; kc < 2; ++kc) {
        bf16x8 bfr[4];
        #pragma unroll
        for (int pj = 0; pj < 4; ++pj) {
            union { bf16x8 v; unsigned short u[8]; } bb;
            #pragma unroll
            for (int e = 0; e < 8; ++e)
                bb.u[e] = ylds[kc * 32 + gq * 8 + e][pxb + pj * 16 + l15];
            bfr[pj] = bb.v;
        }
        #pragma unroll
        for (int mc = 0; mc < 4; ++mc) {
            int mtile = (wv & 3) * 4 + mc;
            bf16x8 a = *reinterpret_cast<const bf16x8*>(
                fwpk + ((mtile * 2 + kc) * 64 + lane) * 8);
            #pragma unroll
            for (int pj = 0; pj < 4; ++pj)        // SWAPPED: D^T = y^T . w^T
                acc[mc][pj] = __builtin_amdgcn_mfma_f32_16x16x32_bf16(bfr[pj], a, acc[mc][pj], 0, 0, 0);
        }
    }

    // lane holds: c = chb + mc*16 + l15, px = pxb + pj*16 + gq*4 + e
    size_t outbase = (size_t)n * C * HW + (size_t)h * WDIM;
    #pragma unroll
    for (int mc = 0; mc < 4; ++mc) {
        int c = chb + mc * 16 + l15;
        float bias = fbe[c];
        #pragma unroll
        for (int pj = 0; pj < 4; ++pj) {
            int w = pxb + pj * 16 + gq * 4;
            f32x4 vv;
            #pragma unroll
            for (int e = 0; e < 4; ++e) vv[e] = acc[mc][pj][e] + bias;
            __builtin_nontemporal_store(vv,
                reinterpret_cast<f32x4*>(&out[outbase + (size_t)c * HW + w]));
        }
    }
}

// ---------------------------------------------------------------------------
extern "C" void kernel_launch(void* const* d_in, const int* in_sizes, int n_in,
                              void* d_out, int out_size, void* d_ws, size_t ws_size,
                              hipStream_t stream) {
    const float* x      = (const float*)d_in[0];
    const float* conv_w = (const float*)d_in[1];
    const float* conv_b = (const float*)d_in[2];
    const float* dw_b   = (const float*)d_in[3];
    const float* fuse_w = (const float*)d_in[4];
    const float* fuse_b = (const float*)d_in[5];
    float* out = (float*)d_out;

    char* ws = (char*)d_ws;
    unsigned short* f_ws = (unsigned short*)ws;                      // 32 MiB
    float* psum          = (float*)(ws + 33554432);                  // 1.57 MiB
    float* gsum          = (float*)(ws + 33554432 + 2097152);        // 36 KiB
    unsigned short* cwpk = (unsigned short*)(ws + 33554432 + 2097152 + 36864);
    unsigned short* fwpk = (unsigned short*)(ws + 33554432 + 2097152 + 36864 + 32768);
    float* fbe           = (float*)(ws + 33554432 + 2097152 + 36864 + 32768 + 32768);

    k0_pack<<<dim3(64), dim3(256), 0, stream>>>(conv_w, fuse_w, fuse_b, dw_b, cwpk, fwpk, fbe);
    k1_conv<<<dim3(1024), dim3(512), 0, stream>>>(x, cwpk, conv_b, f_ws, psum);
    k2_reduce<<<dim3(1024), dim3(128), 0, stream>>>(psum, gsum);
    k3_dwfuse<<<dim3(2048), dim3(512), 0, stream>>>(f_ws, gsum, fwpk, fbe, out);
}

// Round 17
// 155.270 us; speedup vs baseline: 1.0372x; 1.0001x over previous
//
#include <hip/hip_runtime.h>
#include <hip/hip_bf16.h>

#define NB 16
#define C 256
#define C4 64
#define HDIM 128
#define WDIM 128
#define HW 16384

typedef __bf16 bf16x8 __attribute__((ext_vector_type(8)));
typedef float f32x4 __attribute__((ext_vector_type(4)));

__device__ __forceinline__ unsigned short f2bf(float x) {
    union { __bf16 h; unsigned short u; } c;
    c.h = (__bf16)x;                       // RNE
    return c.u;
}
__device__ __forceinline__ float bf2f(unsigned short b) {
    union { float f; unsigned u; } a; a.u = ((unsigned)b) << 16; return a.f;
}

// ---------------------------------------------------------------------------
// Cache policy (established by A/B over R14-R16):
//  - x loads:  NONTEMPORAL. R15 proved plain loads cost +22 us: the 268 MB
//    x stream evicts f (32 MB) from LLC, pushing k3's 96 MB f re-reads to HBM.
//  - f loads/stores: plain (f must stay LLC-resident between k1 and k3).
//  - out stores: NONTEMPORAL (R16 isolated test): out is write-once,
//    never re-read; plain stores allocate 268 MB in LLC during k3 and evict
//    f between its 1st and 3rd read. Same pollution mechanism as x.
// ---------------------------------------------------------------------------

// ---------------------------------------------------------------------------
// K0: pack conv_w (64x256) and fuse_w (256x64) into MFMA fragment order,
// compute fuse_b_eff[c] = fuse_b[c] + sum_o fuse_w[c][o]*dw_b[o].
// Fragment (16x16x32): lane = (i&15) | (((k>>3)&3)<<4), e = k&7. The same
// packed data serves as A-frag of W and B-frag of W^T (layouts are
// transpose-symmetric), which is what lets K1/K3 swap mfma operands freely.
// ---------------------------------------------------------------------------
__global__ __launch_bounds__(256) void k0_pack(
    const float* __restrict__ conv_w, const float* __restrict__ fuse_w,
    const float* __restrict__ fuse_b, const float* __restrict__ dw_b,
    unsigned short* __restrict__ cwpk, unsigned short* __restrict__ fwpk,
    float* __restrict__ fbe)
{
    int tid = blockIdx.x * 256 + threadIdx.x;   // 0..16383
    {   // conv_w: M=64, K=256
        int m = tid >> 8, k = tid & 255;
        int frag = (m >> 4) * 8 + (k >> 5);
        int lane = (m & 15) | (((k >> 3) & 3) << 4);
        int e = k & 7;
        cwpk[(frag * 64 + lane) * 8 + e] = f2bf(conv_w[m * 256 + k]);
    }
    {   // fuse_w: M=256, K=64
        int m = tid >> 6, k = tid & 63;
        int frag = (m >> 4) * 2 + (k >> 5);
        int lane = (m & 15) | (((k >> 3) & 3) << 4);
        int e = k & 7;
        fwpk[(frag * 64 + lane) * 8 + e] = f2bf(fuse_w[m * 64 + k]);
    }
    if (tid < 256) {
        float s = fuse_b[tid];
        #pragma unroll
        for (int o = 0; o < 64; ++o) s += fuse_w[tid * 64 + o] * dw_b[o];
        fbe[tid] = s;
    }
}

// ---------------------------------------------------------------------------
// K1: f = conv1(x) + conv_b  (GEMM, operand-swapped: D^T = x^T . conv_w^T).
// TWO-ROW blocks: 1024 blocks x 512 thr; each channel's x-read is one 1 KB
// run (one full wave-load, nontemporal). Ping-pong LDS, issue-early
// prefetch, ONE barrier/chunk. Pool partials per h-row; xpool aliases the
// staging buffer after the final barrier.
// ---------------------------------------------------------------------------
__global__ __launch_bounds__(512) void k1_conv(
    const float* __restrict__ x, const unsigned short* __restrict__ cwpk,
    const float* __restrict__ conv_b, unsigned short* __restrict__ f_ws,
    float* __restrict__ psum)
{
    __shared__ __align__(16) unsigned short xlds[2][32 * 258];  // 2 x 16512 B
    int blk = blockIdx.x;                         // 1024 = 16 n * 64 hpair
    int n = blk >> 6;
    int h0 = (blk & 63) * 2;
    int p0 = h0 * WDIM;                           // 256 px = two rows
    int t = threadIdx.x;
    int lane = t & 63, wv = t >> 6, gq = lane >> 4, l15 = lane & 15;
    const float* xn = x + (size_t)n * C * HW + p0;

    int lpx = (t & 63) * 4;                       // 0..252: pixel base (f32x4)
    // staging: wave wv loads channels {j*8 + wv}, each 64 lanes x 16 B = 1 KB

    f32x4 r[4];
    #pragma unroll
    for (int j = 0; j < 4; ++j)
        r[j] = __builtin_nontemporal_load(
            reinterpret_cast<const f32x4*>(&xn[(size_t)(j * 8 + wv) * HW + lpx]));

    f32x4 acc[2][4];
    #pragma unroll
    for (int pt = 0; pt < 2; ++pt)
        #pragma unroll
        for (int m = 0; m < 4; ++m) acc[pt][m] = (f32x4){0.f, 0.f, 0.f, 0.f};

    for (int kc = 0; kc < 8; ++kc) {
        unsigned short* buf = xlds[kc & 1];
        unsigned int pk[4][2];
        #pragma unroll
        for (int j = 0; j < 4; ++j) {
            pk[j][0] = ((unsigned)f2bf(r[j].y) << 16) | f2bf(r[j].x);
            pk[j][1] = ((unsigned)f2bf(r[j].w) << 16) | f2bf(r[j].z);
        }
        if (kc < 7) {                  // issue-early: loads fly under barrier+MFMA
            #pragma unroll
            for (int j = 0; j < 4; ++j)
                r[j] = __builtin_nontemporal_load(
                    reinterpret_cast<const f32x4*>(
                        &xn[(size_t)((kc + 1) * 32 + j * 8 + wv) * HW + lpx]));
        }
        #pragma unroll
        for (int j = 0; j < 4; ++j) {
            unsigned int* dst = reinterpret_cast<unsigned int*>(
                &buf[(j * 8 + wv) * 258 + lpx]);
            dst[0] = pk[j][0];
            dst[1] = pk[j][1];
        }
        __syncthreads();                          // tile visible; prev buf free
        bf16x8 a[4];
        #pragma unroll
        for (int m = 0; m < 4; ++m)
            a[m] = *reinterpret_cast<const bf16x8*>(cwpk + ((m * 8 + kc) * 64 + lane) * 8);
        #pragma unroll
        for (int pt = 0; pt < 2; ++pt) {
            int px = wv * 32 + pt * 16 + l15;
            union { bf16x8 v; unsigned short u[8]; } b;
            #pragma unroll
            for (int e = 0; e < 8; ++e)
                b.u[e] = buf[(gq * 8 + e) * 258 + px];
            #pragma unroll
            for (int m = 0; m < 4; ++m)           // SWAPPED: D^T = x^T . w^T
                acc[pt][m] = __builtin_amdgcn_mfma_f32_16x16x32_bf16(b.v, a[m], acc[pt][m], 0, 0, 0);
        }
    }

    // lane holds: o = m*16 + l15, px = wv*32 + pt*16 + gq*4 + e  (row = px>>7)
    float cbv[4];
    #pragma unroll
    for (int m = 0; m < 4; ++m) cbv[m] = conv_b[m * 16 + l15];

    float cs[4][3];
    #pragma unroll
    for (int m = 0; m < 4; ++m) cs[m][0] = cs[m][1] = cs[m][2] = 0.f;

    unsigned short* fn = f_ws + (size_t)n * C4 * HW;
    #pragma unroll
    for (int pt = 0; pt < 2; ++pt) {
        int pxb = wv * 32 + pt * 16 + gq * 4;     // 0..255 within the 2 rows
        int cl = pxb & 127;                       // column within its row
        #pragma unroll
        for (int m = 0; m < 4; ++m) {
            int o = m * 16 + l15;
            union { unsigned int d[2]; unsigned short u[4]; } pk2;
            #pragma unroll
            for (int e = 0; e < 4; ++e) {
                float v = acc[pt][m][e] + cbv[m];
                pk2.u[e] = f2bf(v);
                int col = cl + e;
                if (col < 43)               cs[m][0] += v;
                if (col >= 42 && col < 86)  cs[m][1] += v;
                if (col >= 85)              cs[m][2] += v;
            }
            *reinterpret_cast<uint2*>(&fn[(size_t)o * HW + p0 + pxb]) =
                (uint2){pk2.d[0], pk2.d[1]};
        }
    }

    // reduce col-bin sums over the 4 gq groups (lanes differ in bits 4-5);
    // each wave is entirely within one row: waves 0-3 = row h0, 4-7 = h0+1
    #pragma unroll
    for (int m = 0; m < 4; ++m)
        #pragma unroll
        for (int b = 0; b < 3; ++b) {
            float v = cs[m][b];
            v += __shfl_xor(v, 16, 64);
            v += __shfl_xor(v, 32, 64);
            cs[m][b] = v;
        }

    __syncthreads();                    // all staging reads done -> alias OK
    float (*xpool)[192] = reinterpret_cast<float(*)[192]>(&xlds[0][0]);
    if (gq == 0) {
        #pragma unroll
        for (int m = 0; m < 4; ++m)
            #pragma unroll
            for (int b = 0; b < 3; ++b)
                xpool[wv][(m * 16 + l15) * 3 + b] = cs[m][b];
    }
    __syncthreads();
    if (t < 192) {
        psum[(size_t)(n * 128 + h0) * 192 + t] =
            xpool[0][t] + xpool[1][t] + xpool[2][t] + xpool[3][t];
    } else if (t >= 256 && t < 448) {
        int tt = t - 256;
        psum[(size_t)(n * 128 + h0 + 1) * 192 + tt] =
            xpool[4][tt] + xpool[5][tt] + xpool[6][tt] + xpool[7][tt];
    }
}

// ---------------------------------------------------------------------------
// K2r: gsum[n,o,i,j] = sum over h (with torch-adaptive h-bin overlap: rows
// 42 & 85 belong to two bins) of psum[n*128+h][o*3+b].
// 1024 blocks (one per (n,o)) x 128 threads (one per h).
// ---------------------------------------------------------------------------
__global__ __launch_bounds__(128) void k2_reduce(
    const float* __restrict__ psum, float* __restrict__ gsum)
{
    int bid = blockIdx.x;               // 1024
    int n = bid >> 6, o = bid & 63;
    int h = threadIdx.x;                // 0..127
    const float* ps = psum + ((size_t)(n * 128 + h)) * 192 + o * 3;
    float v0 = ps[0], v1 = ps[1], v2 = ps[2];

    float s[9];
    #pragma unroll
    for (int k = 0; k < 9; ++k) s[k] = 0.f;
    if (h < 43)            { s[0] += v0; s[1] += v1; s[2] += v2; }
    if (h >= 42 && h < 86) { s[3] += v0; s[4] += v1; s[5] += v2; }
    if (h >= 85)           { s[6] += v0; s[7] += v1; s[8] += v2; }

    int lane = h & 63, wid = h >> 6;
    #pragma unroll
    for (int k = 0; k < 9; ++k) {
        float v = s[k];
        for (int off = 32; off > 0; off >>= 1) v += __shfl_down(v, off, 64);
        s[k] = v;
    }
    __shared__ float red[2][9];
    if (lane == 0) {
        #pragma unroll
        for (int k = 0; k < 9; ++k) red[wid][k] = s[k];
    }
    __syncthreads();
    if (threadIdx.x < 9)
        gsum[(n * 64 + o) * 9 + threadIdx.x] = red[0][threadIdx.x] + red[1][threadIdx.x];
}

// ---------------------------------------------------------------------------
// K3: y = depthwise3x3(f, g) ; out = fuse_w . y + fuse_b_eff
// Block: one (n, row h), full 128 cols, 512 threads (8 waves).
// MFMA operand-swapped: D^T = y^T . fuse_w^T -> f32x4 NONTEMPORAL out-stores
// (out is write-once; keeping it out of LLC protects f's residency).
// ---------------------------------------------------------------------------
__global__ __launch_bounds__(512) void k3_dwfuse(
    const unsigned short* __restrict__ f_ws, const float* __restrict__ gsum,
    const unsigned short* __restrict__ fwpk, const float* __restrict__ fbe,
    float* __restrict__ out)
{
    __shared__ unsigned short ylds[64][136];
    int blk = blockIdx.x;                 // 2048
    int n = blk >> 7;
    int h = blk & 127;
    int t = threadIdx.x;

    {   // depthwise: thread t -> channel o = t>>3, strip q = t&7 (16 px)
        const float ginv[9] = {
            1.f/1849.f, 1.f/1892.f, 1.f/1849.f,
            1.f/1892.f, 1.f/1936.f, 1.f/1892.f,
            1.f/1849.f, 1.f/1892.f, 1.f/1849.f };
        int o = t >> 3, q = t & 7;
        int wb = q * 16;
        const unsigned short* fp = f_ws + (size_t)(n * 64 + o) * HW;
        const float* gp = gsum + (n * 64 + o) * 9;
        float gv[9];
        #pragma unroll
        for (int k = 0; k < 9; ++k) gv[k] = gp[k] * ginv[k];
        float y[16];
        #pragma unroll
        for (int i = 0; i < 16; ++i) y[i] = 0.f;
        #pragma unroll
        for (int dy = -1; dy <= 1; ++dy) {
            int hh = h + dy;
            if (hh < 0 || hh >= HDIM) continue;
            const unsigned short* row = fp + hh * WDIM;
            union { uint4 q4; unsigned short u[8]; } bA, bB;
            bA.q4 = *reinterpret_cast<const uint4*>(row + wb);
            bB.q4 = *reinterpret_cast<const uint4*>(row + wb + 8);
            float lft = bf2f(row[wb == 0 ? 0 : wb - 1]);
            if (wb == 0)   lft = 0.f;
            float rgt = bf2f(row[wb == 112 ? 127 : wb + 16]);
            if (wb == 112) rgt = 0.f;
            float rv[18];
            rv[0] = lft;
            #pragma unroll
            for (int z = 0; z < 8; ++z) rv[1 + z] = bf2f(bA.u[z]);
            #pragma unroll
            for (int z = 0; z < 8; ++z) rv[9 + z] = bf2f(bB.u[z]);
            rv[17] = rgt;
            float g0 = gv[(dy + 1) * 3], g1 = gv[(dy + 1) * 3 + 1], g2 = gv[(dy + 1) * 3 + 2];
            #pragma unroll
            for (int i = 0; i < 16; ++i)
                y[i] += g0 * rv[i] + g1 * rv[i + 1] + g2 * rv[i + 2];
        }
        union { uint4 q4[2]; unsigned short u[16]; } pk;
        #pragma unroll
        for (int i = 0; i < 16; ++i) pk.u[i] = f2bf(y[i]);
        *reinterpret_cast<uint4*>(&ylds[o][wb])     = pk.q4[0];
        *reinterpret_cast<uint4*>(&ylds[o][wb + 8]) = pk.q4[1];
    }
    __syncthreads();

    int lane = t & 63, wv = t >> 6, gq = lane >> 4, l15 = lane & 15;
    int chb = (wv & 3) * 64, pxb = (wv >> 2) * 64;
    f32x4 acc[4][4];
    #pragma unroll
    for (int a = 0; a < 4; ++a)
        #pragma unroll
        for (int b = 0; b < 4; ++b) acc[a][b] = (f32x4){0.f,0.f,0.f,0.f};

    #pragma unroll
    for (int kc = 0; kc < 2; ++kc) {
        bf16x8 bfr[4];
        #pragma unroll
        for (int pj = 0; pj < 4; ++pj) {
            union { bf16x8 v; unsigned short u[8]; } bb;
            #pragma unroll
            for (int e = 0; e < 8; ++e)
                bb.u[e] = ylds[kc * 32 + gq * 8 + e][pxb + pj * 16 + l15];
            bfr[pj] = bb.v;
        }
        #pragma unroll
        for (int mc = 0; mc < 4; ++mc) {
            int mtile = (wv & 3) * 4 + mc;
            bf16x8 a = *reinterpret_cast<const bf16x8*>(
                fwpk + ((mtile * 2 + kc) * 64 + lane) * 8);
            #pragma unroll
            for (int pj = 0; pj < 4; ++pj)        // SWAPPED: D^T = y^T . w^T
                acc[mc][pj] = __builtin_amdgcn_mfma_f32_16x16x32_bf16(bfr[pj], a, acc[mc][pj], 0, 0, 0);
        }
    }

    // lane holds: c = chb + mc*16 + l15, px = pxb + pj*16 + gq*4 + e
    size_t outbase = (size_t)n * C * HW + (size_t)h * WDIM;
    #pragma unroll
    for (int mc = 0; mc < 4; ++mc) {
        int c = chb + mc * 16 + l15;
        float bias = fbe[c];
        #pragma unroll
        for (int pj = 0; pj < 4; ++pj) {
            int w = pxb + pj * 16 + gq * 4;
            f32x4 vv;
            #pragma unroll
            for (int e = 0; e < 4; ++e) vv[e] = acc[mc][pj][e] + bias;
            __builtin_nontemporal_store(vv,
                reinterpret_cast<f32x4*>(&out[outbase + (size_t)c * HW + w]));
        }
    }
}

// ---------------------------------------------------------------------------
extern "C" void kernel_launch(void* const* d_in, const int* in_sizes, int n_in,
                              void* d_out, int out_size, void* d_ws, size_t ws_size,
                              hipStream_t stream) {
    const float* x      = (const float*)d_in[0];
    const float* conv_w = (const float*)d_in[1];
    const float* conv_b = (const float*)d_in[2];
    const float* dw_b   = (const float*)d_in[3];
    const float* fuse_w = (const float*)d_in[4];
    const float* fuse_b = (const float*)d_in[5];
    float* out = (float*)d_out;

    char* ws = (char*)d_ws;
    unsigned short* f_ws = (unsigned short*)ws;                      // 32 MiB
    float* psum          = (float*)(ws + 33554432);                  // 1.57 MiB
    float* gsum          = (float*)(ws + 33554432 + 2097152);        // 36 KiB
    unsigned short* cwpk = (unsigned short*)(ws + 33554432 + 2097152 + 36864);
    unsigned short* fwpk = (unsigned short*)(ws + 33554432 + 2097152 + 36864 + 32768);
    float* fbe           = (float*)(ws + 33554432 + 2097152 + 36864 + 32768 + 32768);

    k0_pack<<<dim3(64), dim3(256), 0, stream>>>(conv_w, fuse_w, fuse_b, dw_b, cwpk, fwpk, fbe);
    k1_conv<<<dim3(1024), dim3(512), 0, stream>>>(x, cwpk, conv_b, f_ws, psum);
    k2_reduce<<<dim3(1024), dim3(128), 0, stream>>>(psum, gsum);
    k3_dwfuse<<<dim3(2048), dim3(512), 0, stream>>>(f_ws, gsum, fwpk, fbe, out);
}

// Round 18
// 142.963 us; speedup vs baseline: 1.1265x; 1.0861x over previous
//
#include <hip/hip_runtime.h>
#include <hip/hip_bf16.h>

#define NB 16
#define C 256
#define C4 64
#define HDIM 128
#define WDIM 128
#define HW 16384

typedef __bf16 bf16x8 __attribute__((ext_vector_type(8)));
typedef float f32x4 __attribute__((ext_vector_type(4)));

__device__ __forceinline__ unsigned short f2bf(float x) {
    union { __bf16 h; unsigned short u; } c;
    c.h = (__bf16)x;                       // RNE
    return c.u;
}
__device__ __forceinline__ float bf2f(unsigned short b) {
    union { float f; unsigned u; } a; a.u = ((unsigned)b) << 16; return a.f;
}

// ---------------------------------------------------------------------------
// Cache policy (A/B-proven over R14-R17):
//  - x loads:  NONTEMPORAL. Plain loads cost +22 us (R15): 268 MB x stream
//    evicts f (32 MB) from LLC -> k3's f re-reads go to HBM.
//  - f loads/stores: plain (must stay LLC-resident between k1 and k3).
//  - out stores: PLAIN. NT stores cost +17 us (R17): they bypass L2
//    write-combining, so each 64 B channel-segment goes to HBM as a partial
//    burst. Plain stores let L2 merge adjacent segments into full lines.
// ---------------------------------------------------------------------------

// ---------------------------------------------------------------------------
// K0: pack conv_w (64x256) and fuse_w (256x64) into MFMA fragment order,
// compute fuse_b_eff[c] = fuse_b[c] + sum_o fuse_w[c][o]*dw_b[o].
// Fragment (16x16x32): lane = (i&15) | (((k>>3)&3)<<4), e = k&7. The same
// packed data serves as A-frag of W and B-frag of W^T (layouts are
// transpose-symmetric), which is what lets K1/K3 swap mfma operands freely.
// ---------------------------------------------------------------------------
__global__ __launch_bounds__(256) void k0_pack(
    const float* __restrict__ conv_w, const float* __restrict__ fuse_w,
    const float* __restrict__ fuse_b, const float* __restrict__ dw_b,
    unsigned short* __restrict__ cwpk, unsigned short* __restrict__ fwpk,
    float* __restrict__ fbe)
{
    int tid = blockIdx.x * 256 + threadIdx.x;   // 0..16383
    {   // conv_w: M=64, K=256
        int m = tid >> 8, k = tid & 255;
        int frag = (m >> 4) * 8 + (k >> 5);
        int lane = (m & 15) | (((k >> 3) & 3) << 4);
        int e = k & 7;
        cwpk[(frag * 64 + lane) * 8 + e] = f2bf(conv_w[m * 256 + k]);
    }
    {   // fuse_w: M=256, K=64
        int m = tid >> 6, k = tid & 63;
        int frag = (m >> 4) * 2 + (k >> 5);
        int lane = (m & 15) | (((k >> 3) & 3) << 4);
        int e = k & 7;
        fwpk[(frag * 64 + lane) * 8 + e] = f2bf(fuse_w[m * 64 + k]);
    }
    if (tid < 256) {
        float s = fuse_b[tid];
        #pragma unroll
        for (int o = 0; o < 64; ++o) s += fuse_w[tid * 64 + o] * dw_b[o];
        fbe[tid] = s;
    }
}

// ---------------------------------------------------------------------------
// K1: f = conv1(x) + conv_b  (GEMM, operand-swapped: D^T = x^T . conv_w^T).
// TWO-ROW blocks: 1024 blocks x 512 thr; each channel's x-read is one 1 KB
// run (one full wave-load, nontemporal). Ping-pong LDS, issue-early
// prefetch, ONE barrier/chunk. Pool partials per h-row; xpool aliases the
// staging buffer after the final barrier.  (= R14 proven-best config)
// ---------------------------------------------------------------------------
__global__ __launch_bounds__(512) void k1_conv(
    const float* __restrict__ x, const unsigned short* __restrict__ cwpk,
    const float* __restrict__ conv_b, unsigned short* __restrict__ f_ws,
    float* __restrict__ psum)
{
    __shared__ __align__(16) unsigned short xlds[2][32 * 258];  // 2 x 16512 B
    int blk = blockIdx.x;                         // 1024 = 16 n * 64 hpair
    int n = blk >> 6;
    int h0 = (blk & 63) * 2;
    int p0 = h0 * WDIM;                           // 256 px = two rows
    int t = threadIdx.x;
    int lane = t & 63, wv = t >> 6, gq = lane >> 4, l15 = lane & 15;
    const float* xn = x + (size_t)n * C * HW + p0;

    int lpx = (t & 63) * 4;                       // 0..252: pixel base (f32x4)

    f32x4 r[4];
    #pragma unroll
    for (int j = 0; j < 4; ++j)
        r[j] = __builtin_nontemporal_load(
            reinterpret_cast<const f32x4*>(&xn[(size_t)(j * 8 + wv) * HW + lpx]));

    f32x4 acc[2][4];
    #pragma unroll
    for (int pt = 0; pt < 2; ++pt)
        #pragma unroll
        for (int m = 0; m < 4; ++m) acc[pt][m] = (f32x4){0.f, 0.f, 0.f, 0.f};

    for (int kc = 0; kc < 8; ++kc) {
        unsigned short* buf = xlds[kc & 1];
        unsigned int pk[4][2];
        #pragma unroll
        for (int j = 0; j < 4; ++j) {
            pk[j][0] = ((unsigned)f2bf(r[j].y) << 16) | f2bf(r[j].x);
            pk[j][1] = ((unsigned)f2bf(r[j].w) << 16) | f2bf(r[j].z);
        }
        if (kc < 7) {                  // issue-early: loads fly under barrier+MFMA
            #pragma unroll
            for (int j = 0; j < 4; ++j)
                r[j] = __builtin_nontemporal_load(
                    reinterpret_cast<const f32x4*>(
                        &xn[(size_t)((kc + 1) * 32 + j * 8 + wv) * HW + lpx]));
        }
        #pragma unroll
        for (int j = 0; j < 4; ++j) {
            unsigned int* dst = reinterpret_cast<unsigned int*>(
                &buf[(j * 8 + wv) * 258 + lpx]);
            dst[0] = pk[j][0];
            dst[1] = pk[j][1];
        }
        __syncthreads();                          // tile visible; prev buf free
        bf16x8 a[4];
        #pragma unroll
        for (int m = 0; m < 4; ++m)
            a[m] = *reinterpret_cast<const bf16x8*>(cwpk + ((m * 8 + kc) * 64 + lane) * 8);
        #pragma unroll
        for (int pt = 0; pt < 2; ++pt) {
            int px = wv * 32 + pt * 16 + l15;
            union { bf16x8 v; unsigned short u[8]; } b;
            #pragma unroll
            for (int e = 0; e < 8; ++e)
                b.u[e] = buf[(gq * 8 + e) * 258 + px];
            #pragma unroll
            for (int m = 0; m < 4; ++m)           // SWAPPED: D^T = x^T . w^T
                acc[pt][m] = __builtin_amdgcn_mfma_f32_16x16x32_bf16(b.v, a[m], acc[pt][m], 0, 0, 0);
        }
    }

    // lane holds: o = m*16 + l15, px = wv*32 + pt*16 + gq*4 + e  (row = px>>7)
    float cbv[4];
    #pragma unroll
    for (int m = 0; m < 4; ++m) cbv[m] = conv_b[m * 16 + l15];

    float cs[4][3];
    #pragma unroll
    for (int m = 0; m < 4; ++m) cs[m][0] = cs[m][1] = cs[m][2] = 0.f;

    unsigned short* fn = f_ws + (size_t)n * C4 * HW;
    #pragma unroll
    for (int pt = 0; pt < 2; ++pt) {
        int pxb = wv * 32 + pt * 16 + gq * 4;     // 0..255 within the 2 rows
        int cl = pxb & 127;                       // column within its row
        #pragma unroll
        for (int m = 0; m < 4; ++m) {
            int o = m * 16 + l15;
            union { unsigned int d[2]; unsigned short u[4]; } pk2;
            #pragma unroll
            for (int e = 0; e < 4; ++e) {
                float v = acc[pt][m][e] + cbv[m];
                pk2.u[e] = f2bf(v);
                int col = cl + e;
                if (col < 43)               cs[m][0] += v;
                if (col >= 42 && col < 86)  cs[m][1] += v;
                if (col >= 85)              cs[m][2] += v;
            }
            *reinterpret_cast<uint2*>(&fn[(size_t)o * HW + p0 + pxb]) =
                (uint2){pk2.d[0], pk2.d[1]};
        }
    }

    // reduce col-bin sums over the 4 gq groups (lanes differ in bits 4-5);
    // each wave is entirely within one row: waves 0-3 = row h0, 4-7 = h0+1
    #pragma unroll
    for (int m = 0; m < 4; ++m)
        #pragma unroll
        for (int b = 0; b < 3; ++b) {
            float v = cs[m][b];
            v += __shfl_xor(v, 16, 64);
            v += __shfl_xor(v, 32, 64);
            cs[m][b] = v;
        }

    __syncthreads();                    // all staging reads done -> alias OK
    float (*xpool)[192] = reinterpret_cast<float(*)[192]>(&xlds[0][0]);
    if (gq == 0) {
        #pragma unroll
        for (int m = 0; m < 4; ++m)
            #pragma unroll
            for (int b = 0; b < 3; ++b)
                xpool[wv][(m * 16 + l15) * 3 + b] = cs[m][b];
    }
    __syncthreads();
    if (t < 192) {
        psum[(size_t)(n * 128 + h0) * 192 + t] =
            xpool[0][t] + xpool[1][t] + xpool[2][t] + xpool[3][t];
    } else if (t >= 256 && t < 448) {
        int tt = t - 256;
        psum[(size_t)(n * 128 + h0 + 1) * 192 + tt] =
            xpool[4][tt] + xpool[5][tt] + xpool[6][tt] + xpool[7][tt];
    }
}

// ---------------------------------------------------------------------------
// K2r: gsum[n,o,i,j] = sum over h (with torch-adaptive h-bin overlap: rows
// 42 & 85 belong to two bins) of psum[n*128+h][o*3+b].
// 1024 blocks (one per (n,o)) x 128 threads (one per h).
// ---------------------------------------------------------------------------
__global__ __launch_bounds__(128) void k2_reduce(
    const float* __restrict__ psum, float* __restrict__ gsum)
{
    int bid = blockIdx.x;               // 1024
    int n = bid >> 6, o = bid & 63;
    int h = threadIdx.x;                // 0..127
    const float* ps = psum + ((size_t)(n * 128 + h)) * 192 + o * 3;
    float v0 = ps[0], v1 = ps[1], v2 = ps[2];

    float s[9];
    #pragma unroll
    for (int k = 0; k < 9; ++k) s[k] = 0.f;
    if (h < 43)            { s[0] += v0; s[1] += v1; s[2] += v2; }
    if (h >= 42 && h < 86) { s[3] += v0; s[4] += v1; s[5] += v2; }
    if (h >= 85)           { s[6] += v0; s[7] += v1; s[8] += v2; }

    int lane = h & 63, wid = h >> 6;
    #pragma unroll
    for (int k = 0; k < 9; ++k) {
        float v = s[k];
        for (int off = 32; off > 0; off >>= 1) v += __shfl_down(v, off, 64);
        s[k] = v;
    }
    __shared__ float red[2][9];
    if (lane == 0) {
        #pragma unroll
        for (int k = 0; k < 9; ++k) red[wid][k] = s[k];
    }
    __syncthreads();
    if (threadIdx.x < 9)
        gsum[(n * 64 + o) * 9 + threadIdx.x] = red[0][threadIdx.x] + red[1][threadIdx.x];
}

// ---------------------------------------------------------------------------
// K3: y = depthwise3x3(f, g) ; out = fuse_w . y + fuse_b_eff
// TWO-ROW blocks (R18): 1024 blocks x 1024 thr (16 waves). Per 2 output rows
// the block touches 4 f rows (vs 3 per 1 row before) -> f LLC traffic
// 96 -> 64 MB; shared middle rows are L1-hits within the block. ylds [64][264]
// holds both rows (px 0..127 = row h0, 128..255 = row h0+1); 33.8 KB LDS ->
// 2 blocks/CU x 16 waves = 32 waves/CU (occupancy unchanged vs R14).
// MFMA operand-swapped: D^T = y^T . fuse_w^T -> f32x4 plain out-stores;
// each wave's 64-px quadrant lies entirely within one row.
// ---------------------------------------------------------------------------
__global__ __launch_bounds__(1024) void k3_dwfuse(
    const unsigned short* __restrict__ f_ws, const float* __restrict__ gsum,
    const unsigned short* __restrict__ fwpk, const float* __restrict__ fbe,
    float* __restrict__ out)
{
    __shared__ unsigned short ylds[64][264];
    int blk = blockIdx.x;                 // 1024 = 16 n * 64 hpair
    int n = blk >> 6;
    int h0 = (blk & 63) * 2;
    int t = threadIdx.x;

    {   // depthwise: thread t -> channel o = t>>4, row sub = (t>>3)&1,
        // strip q = t&7 (16 px of row h0+sub)
        const float ginv[9] = {
            1.f/1849.f, 1.f/1892.f, 1.f/1849.f,
            1.f/1892.f, 1.f/1936.f, 1.f/1892.f,
            1.f/1849.f, 1.f/1892.f, 1.f/1849.f };
        int o = t >> 4, sub = (t >> 3) & 1, q = t & 7;
        int h = h0 + sub;
        int wb = q * 16;
        const unsigned short* fp = f_ws + (size_t)(n * 64 + o) * HW;
        const float* gp = gsum + (n * 64 + o) * 9;
        float gv[9];
        #pragma unroll
        for (int k = 0; k < 9; ++k) gv[k] = gp[k] * ginv[k];
        float y[16];
        #pragma unroll
        for (int i = 0; i < 16; ++i) y[i] = 0.f;
        #pragma unroll
        for (int dy = -1; dy <= 1; ++dy) {
            int hh = h + dy;
            if (hh < 0 || hh >= HDIM) continue;
            const unsigned short* row = fp + hh * WDIM;
            union { uint4 q4; unsigned short u[8]; } bA, bB;
            bA.q4 = *reinterpret_cast<const uint4*>(row + wb);
            bB.q4 = *reinterpret_cast<const uint4*>(row + wb + 8);
            float lft = bf2f(row[wb == 0 ? 0 : wb - 1]);
            if (wb == 0)   lft = 0.f;
            float rgt = bf2f(row[wb == 112 ? 127 : wb + 16]);
            if (wb == 112) rgt = 0.f;
            float rv[18];
            rv[0] = lft;
            #pragma unroll
            for (int z = 0; z < 8; ++z) rv[1 + z] = bf2f(bA.u[z]);
            #pragma unroll
            for (int z = 0; z < 8; ++z) rv[9 + z] = bf2f(bB.u[z]);
            rv[17] = rgt;
            float g0 = gv[(dy + 1) * 3], g1 = gv[(dy + 1) * 3 + 1], g2 = gv[(dy + 1) * 3 + 2];
            #pragma unroll
            for (int i = 0; i < 16; ++i)
                y[i] += g0 * rv[i] + g1 * rv[i + 1] + g2 * rv[i + 2];
        }
        union { uint4 q4[2]; unsigned short u[16]; } pk;
        #pragma unroll
        for (int i = 0; i < 16; ++i) pk.u[i] = f2bf(y[i]);
        int pxb = sub * 128 + wb;
        *reinterpret_cast<uint4*>(&ylds[o][pxb])     = pk.q4[0];
        *reinterpret_cast<uint4*>(&ylds[o][pxb + 8]) = pk.q4[1];
    }
    __syncthreads();

    int lane = t & 63, wv = t >> 6, gq = lane >> 4, l15 = lane & 15;
    int chb = (wv & 3) * 64, pxb = (wv >> 2) * 64;    // pxb 0..192 (2 rows)
    f32x4 acc[4][4];
    #pragma unroll
    for (int a = 0; a < 4; ++a)
        #pragma unroll
        for (int b = 0; b < 4; ++b) acc[a][b] = (f32x4){0.f,0.f,0.f,0.f};

    #pragma unroll
    for (int kc = 0; kc < 2; ++kc) {
        bf16x8 bfr[4];
        #pragma unroll
        for (int pj = 0; pj < 4; ++pj) {
            union { bf16x8 v; unsigned short u[8]; } bb;
            #pragma unroll
            for (int e = 0; e < 8; ++e)
                bb.u[e] = ylds[kc * 32 + gq * 8 + e][pxb + pj * 16 + l15];
            bfr[pj] = bb.v;
        }
        #pragma unroll
        for (int mc = 0; mc < 4; ++mc) {
            int mtile = (wv & 3) * 4 + mc;
            bf16x8 a = *reinterpret_cast<const bf16x8*>(
                fwpk + ((mtile * 2 + kc) * 64 + lane) * 8);
            #pragma unroll
            for (int pj = 0; pj < 4; ++pj)        // SWAPPED: D^T = y^T . w^T
                acc[mc][pj] = __builtin_amdgcn_mfma_f32_16x16x32_bf16(bfr[pj], a, acc[mc][pj], 0, 0, 0);
        }
    }

    // lane holds: c = chb + mc*16 + l15, px = pxb + pj*16 + gq*4 + e
    // wave's px quadrant is within one row: row = h0 + (pxb>>7)
    int hrow = h0 + (pxb >> 7);
    int colb = pxb & 127;
    size_t outbase = (size_t)n * C * HW + (size_t)hrow * WDIM;
    #pragma unroll
    for (int mc = 0; mc < 4; ++mc) {
        int c = chb + mc * 16 + l15;
        float bias = fbe[c];
        #pragma unroll
        for (int pj = 0; pj < 4; ++pj) {
            int w = colb + pj * 16 + gq * 4;
            f32x4 vv;
            #pragma unroll
            for (int e = 0; e < 4; ++e) vv[e] = acc[mc][pj][e] + bias;
            *reinterpret_cast<f32x4*>(&out[outbase + (size_t)c * HW + w]) = vv;
        }
    }
}

// ---------------------------------------------------------------------------
extern "C" void kernel_launch(void* const* d_in, const int* in_sizes, int n_in,
                              void* d_out, int out_size, void* d_ws, size_t ws_size,
                              hipStream_t stream) {
    const float* x      = (const float*)d_in[0];
    const float* conv_w = (const float*)d_in[1];
    const float* conv_b = (const float*)d_in[2];
    const float* dw_b   = (const float*)d_in[3];
    const float* fuse_w = (const float*)d_in[4];
    const float* fuse_b = (const float*)d_in[5];
    float* out = (float*)d_out;

    char* ws = (char*)d_ws;
    unsigned short* f_ws = (unsigned short*)ws;                      // 32 MiB
    float* psum          = (float*)(ws + 33554432);                  // 1.57 MiB
    float* gsum          = (float*)(ws + 33554432 + 2097152);        // 36 KiB
    unsigned short* cwpk = (unsigned short*)(ws + 33554432 + 2097152 + 36864);
    unsigned short* fwpk = (unsigned short*)(ws + 33554432 + 2097152 + 36864 + 32768);
    float* fbe           = (float*)(ws + 33554432 + 2097152 + 36864 + 32768 + 32768);

    k0_pack<<<dim3(64), dim3(256), 0, stream>>>(conv_w, fuse_w, fuse_b, dw_b, cwpk, fwpk, fbe);
    k1_conv<<<dim3(1024), dim3(512), 0, stream>>>(x, cwpk, conv_b, f_ws, psum);
    k2_reduce<<<dim3(1024), dim3(128), 0, stream>>>(psum, gsum);
    k3_dwfuse<<<dim3(1024), dim3(1024), 0, stream>>>(f_ws, gsum, fwpk, fbe, out);
}

// Round 19
// 138.335 us; speedup vs baseline: 1.1642x; 1.0335x over previous
//
#include <hip/hip_runtime.h>
#include <hip/hip_bf16.h>

#define NB 16
#define C 256
#define C4 64
#define HDIM 128
#define WDIM 128
#define HW 16384

typedef __bf16 bf16x8 __attribute__((ext_vector_type(8)));
typedef float f32x4 __attribute__((ext_vector_type(4)));

__device__ __forceinline__ unsigned short f2bf(float x) {
    union { __bf16 h; unsigned short u; } c;
    c.h = (__bf16)x;                       // RNE
    return c.u;
}
__device__ __forceinline__ float bf2f(unsigned short b) {
    union { float f; unsigned u; } a; a.u = ((unsigned)b) << 16; return a.f;
}

// ---------------------------------------------------------------------------
// Final configuration = R14 proven best (138.6 us). A/B ledger (R10-R18):
//  - x loads NONTEMPORAL: plain costs +22 us (268 MB x stream evicts f from
//    LLC -> k3's 96 MB f re-reads go to HBM).                          [R15]
//  - out stores PLAIN: NT costs +17 us (bypasses L2 write-combining ->
//    64 B partial bursts to HBM).                                      [R17]
//  - f plain everywhere; halving its re-read traffic = no gain (LLC/L1
//    already absorb it) -> k3 is out-store-bound.                      [R18]
//  - XCD swizzle: -5.7 us regression (x streaming defeats L2 pinning). [R11]
//  - device-scope atomics for pool: catastrophic (+120 us, cross-XCD
//    line ping-pong) -> block-private partials + parallel reduce.    [R8-10]
//  - k1 pipeline variants (barrier count, issue-early, run length):
//    all neutral -> k1 sits at its mixed-stream read envelope.     [R12-14]
// ---------------------------------------------------------------------------

// ---------------------------------------------------------------------------
// K0: pack conv_w (64x256) and fuse_w (256x64) into MFMA fragment order,
// compute fuse_b_eff[c] = fuse_b[c] + sum_o fuse_w[c][o]*dw_b[o].
// Fragment (16x16x32): lane = (i&15) | (((k>>3)&3)<<4), e = k&7. The same
// packed data serves as A-frag of W and B-frag of W^T (layouts are
// transpose-symmetric), which is what lets K1/K3 swap mfma operands freely.
// ---------------------------------------------------------------------------
__global__ __launch_bounds__(256) void k0_pack(
    const float* __restrict__ conv_w, const float* __restrict__ fuse_w,
    const float* __restrict__ fuse_b, const float* __restrict__ dw_b,
    unsigned short* __restrict__ cwpk, unsigned short* __restrict__ fwpk,
    float* __restrict__ fbe)
{
    int tid = blockIdx.x * 256 + threadIdx.x;   // 0..16383
    {   // conv_w: M=64, K=256
        int m = tid >> 8, k = tid & 255;
        int frag = (m >> 4) * 8 + (k >> 5);
        int lane = (m & 15) | (((k >> 3) & 3) << 4);
        int e = k & 7;
        cwpk[(frag * 64 + lane) * 8 + e] = f2bf(conv_w[m * 256 + k]);
    }
    {   // fuse_w: M=256, K=64
        int m = tid >> 6, k = tid & 63;
        int frag = (m >> 4) * 2 + (k >> 5);
        int lane = (m & 15) | (((k >> 3) & 3) << 4);
        int e = k & 7;
        fwpk[(frag * 64 + lane) * 8 + e] = f2bf(fuse_w[m * 64 + k]);
    }
    if (tid < 256) {
        float s = fuse_b[tid];
        #pragma unroll
        for (int o = 0; o < 64; ++o) s += fuse_w[tid * 64 + o] * dw_b[o];
        fbe[tid] = s;
    }
}

// ---------------------------------------------------------------------------
// K1: f = conv1(x) + conv_b  (GEMM, operand-swapped: D^T = x^T . conv_w^T).
// TWO-ROW blocks: 1024 blocks x 512 thr; each channel's x-read is one 1 KB
// run (one full wave-load, nontemporal). Ping-pong LDS, issue-early
// prefetch, ONE barrier/chunk. Pool partials per h-row; xpool aliases the
// staging buffer after the final barrier.
// ---------------------------------------------------------------------------
__global__ __launch_bounds__(512) void k1_conv(
    const float* __restrict__ x, const unsigned short* __restrict__ cwpk,
    const float* __restrict__ conv_b, unsigned short* __restrict__ f_ws,
    float* __restrict__ psum)
{
    __shared__ __align__(16) unsigned short xlds[2][32 * 258];  // 2 x 16512 B
    int blk = blockIdx.x;                         // 1024 = 16 n * 64 hpair
    int n = blk >> 6;
    int h0 = (blk & 63) * 2;
    int p0 = h0 * WDIM;                           // 256 px = two rows
    int t = threadIdx.x;
    int lane = t & 63, wv = t >> 6, gq = lane >> 4, l15 = lane & 15;
    const float* xn = x + (size_t)n * C * HW + p0;

    int lpx = (t & 63) * 4;                       // 0..252: pixel base (f32x4)

    f32x4 r[4];
    #pragma unroll
    for (int j = 0; j < 4; ++j)
        r[j] = __builtin_nontemporal_load(
            reinterpret_cast<const f32x4*>(&xn[(size_t)(j * 8 + wv) * HW + lpx]));

    f32x4 acc[2][4];
    #pragma unroll
    for (int pt = 0; pt < 2; ++pt)
        #pragma unroll
        for (int m = 0; m < 4; ++m) acc[pt][m] = (f32x4){0.f, 0.f, 0.f, 0.f};

    for (int kc = 0; kc < 8; ++kc) {
        unsigned short* buf = xlds[kc & 1];
        unsigned int pk[4][2];
        #pragma unroll
        for (int j = 0; j < 4; ++j) {
            pk[j][0] = ((unsigned)f2bf(r[j].y) << 16) | f2bf(r[j].x);
            pk[j][1] = ((unsigned)f2bf(r[j].w) << 16) | f2bf(r[j].z);
        }
        if (kc < 7) {                  // issue-early: loads fly under barrier+MFMA
            #pragma unroll
            for (int j = 0; j < 4; ++j)
                r[j] = __builtin_nontemporal_load(
                    reinterpret_cast<const f32x4*>(
                        &xn[(size_t)((kc + 1) * 32 + j * 8 + wv) * HW + lpx]));
        }
        #pragma unroll
        for (int j = 0; j < 4; ++j) {
            unsigned int* dst = reinterpret_cast<unsigned int*>(
                &buf[(j * 8 + wv) * 258 + lpx]);
            dst[0] = pk[j][0];
            dst[1] = pk[j][1];
        }
        __syncthreads();                          // tile visible; prev buf free
        bf16x8 a[4];
        #pragma unroll
        for (int m = 0; m < 4; ++m)
            a[m] = *reinterpret_cast<const bf16x8*>(cwpk + ((m * 8 + kc) * 64 + lane) * 8);
        #pragma unroll
        for (int pt = 0; pt < 2; ++pt) {
            int px = wv * 32 + pt * 16 + l15;
            union { bf16x8 v; unsigned short u[8]; } b;
            #pragma unroll
            for (int e = 0; e < 8; ++e)
                b.u[e] = buf[(gq * 8 + e) * 258 + px];
            #pragma unroll
            for (int m = 0; m < 4; ++m)           // SWAPPED: D^T = x^T . w^T
                acc[pt][m] = __builtin_amdgcn_mfma_f32_16x16x32_bf16(b.v, a[m], acc[pt][m], 0, 0, 0);
        }
    }

    // lane holds: o = m*16 + l15, px = wv*32 + pt*16 + gq*4 + e  (row = px>>7)
    float cbv[4];
    #pragma unroll
    for (int m = 0; m < 4; ++m) cbv[m] = conv_b[m * 16 + l15];

    float cs[4][3];
    #pragma unroll
    for (int m = 0; m < 4; ++m) cs[m][0] = cs[m][1] = cs[m][2] = 0.f;

    unsigned short* fn = f_ws + (size_t)n * C4 * HW;
    #pragma unroll
    for (int pt = 0; pt < 2; ++pt) {
        int pxb = wv * 32 + pt * 16 + gq * 4;     // 0..255 within the 2 rows
        int cl = pxb & 127;                       // column within its row
        #pragma unroll
        for (int m = 0; m < 4; ++m) {
            int o = m * 16 + l15;
            union { unsigned int d[2]; unsigned short u[4]; } pk2;
            #pragma unroll
            for (int e = 0; e < 4; ++e) {
                float v = acc[pt][m][e] + cbv[m];
                pk2.u[e] = f2bf(v);
                int col = cl + e;
                if (col < 43)               cs[m][0] += v;
                if (col >= 42 && col < 86)  cs[m][1] += v;
                if (col >= 85)              cs[m][2] += v;
            }
            *reinterpret_cast<uint2*>(&fn[(size_t)o * HW + p0 + pxb]) =
                (uint2){pk2.d[0], pk2.d[1]};
        }
    }

    // reduce col-bin sums over the 4 gq groups (lanes differ in bits 4-5);
    // each wave is entirely within one row: waves 0-3 = row h0, 4-7 = h0+1
    #pragma unroll
    for (int m = 0; m < 4; ++m)
        #pragma unroll
        for (int b = 0; b < 3; ++b) {
            float v = cs[m][b];
            v += __shfl_xor(v, 16, 64);
            v += __shfl_xor(v, 32, 64);
            cs[m][b] = v;
        }

    __syncthreads();                    // all staging reads done -> alias OK
    float (*xpool)[192] = reinterpret_cast<float(*)[192]>(&xlds[0][0]);
    if (gq == 0) {
        #pragma unroll
        for (int m = 0; m < 4; ++m)
            #pragma unroll
            for (int b = 0; b < 3; ++b)
                xpool[wv][(m * 16 + l15) * 3 + b] = cs[m][b];
    }
    __syncthreads();
    if (t < 192) {
        psum[(size_t)(n * 128 + h0) * 192 + t] =
            xpool[0][t] + xpool[1][t] + xpool[2][t] + xpool[3][t];
    } else if (t >= 256 && t < 448) {
        int tt = t - 256;
        psum[(size_t)(n * 128 + h0 + 1) * 192 + tt] =
            xpool[4][tt] + xpool[5][tt] + xpool[6][tt] + xpool[7][tt];
    }
}

// ---------------------------------------------------------------------------
// K2r: gsum[n,o,i,j] = sum over h (with torch-adaptive h-bin overlap: rows
// 42 & 85 belong to two bins) of psum[n*128+h][o*3+b].
// 1024 blocks (one per (n,o)) x 128 threads (one per h).
// ---------------------------------------------------------------------------
__global__ __launch_bounds__(128) void k2_reduce(
    const float* __restrict__ psum, float* __restrict__ gsum)
{
    int bid = blockIdx.x;               // 1024
    int n = bid >> 6, o = bid & 63;
    int h = threadIdx.x;                // 0..127
    const float* ps = psum + ((size_t)(n * 128 + h)) * 192 + o * 3;
    float v0 = ps[0], v1 = ps[1], v2 = ps[2];

    float s[9];
    #pragma unroll
    for (int k = 0; k < 9; ++k) s[k] = 0.f;
    if (h < 43)            { s[0] += v0; s[1] += v1; s[2] += v2; }
    if (h >= 42 && h < 86) { s[3] += v0; s[4] += v1; s[5] += v2; }
    if (h >= 85)           { s[6] += v0; s[7] += v1; s[8] += v2; }

    int lane = h & 63, wid = h >> 6;
    #pragma unroll
    for (int k = 0; k < 9; ++k) {
        float v = s[k];
        for (int off = 32; off > 0; off >>= 1) v += __shfl_down(v, off, 64);
        s[k] = v;
    }
    __shared__ float red[2][9];
    if (lane == 0) {
        #pragma unroll
        for (int k = 0; k < 9; ++k) red[wid][k] = s[k];
    }
    __syncthreads();
    if (threadIdx.x < 9)
        gsum[(n * 64 + o) * 9 + threadIdx.x] = red[0][threadIdx.x] + red[1][threadIdx.x];
}

// ---------------------------------------------------------------------------
// K3: y = depthwise3x3(f, g) ; out = fuse_w . y + fuse_b_eff
// Block: one (n, row h), full 128 cols, 512 threads (8 waves).
// MFMA operand-swapped: D^T = y^T . fuse_w^T -> f32x4 plain out-stores
// (L2 merges per-channel 64 B segments into full lines).  (= R14 config)
// ---------------------------------------------------------------------------
__global__ __launch_bounds__(512) void k3_dwfuse(
    const unsigned short* __restrict__ f_ws, const float* __restrict__ gsum,
    const unsigned short* __restrict__ fwpk, const float* __restrict__ fbe,
    float* __restrict__ out)
{
    __shared__ unsigned short ylds[64][136];
    int blk = blockIdx.x;                 // 2048
    int n = blk >> 7;
    int h = blk & 127;
    int t = threadIdx.x;

    {   // depthwise: thread t -> channel o = t>>3, strip q = t&7 (16 px)
        const float ginv[9] = {
            1.f/1849.f, 1.f/1892.f, 1.f/1849.f,
            1.f/1892.f, 1.f/1936.f, 1.f/1892.f,
            1.f/1849.f, 1.f/1892.f, 1.f/1849.f };
        int o = t >> 3, q = t & 7;
        int wb = q * 16;
        const unsigned short* fp = f_ws + (size_t)(n * 64 + o) * HW;
        const float* gp = gsum + (n * 64 + o) * 9;
        float gv[9];
        #pragma unroll
        for (int k = 0; k < 9; ++k) gv[k] = gp[k] * ginv[k];
        float y[16];
        #pragma unroll
        for (int i = 0; i < 16; ++i) y[i] = 0.f;
        #pragma unroll
        for (int dy = -1; dy <= 1; ++dy) {
            int hh = h + dy;
            if (hh < 0 || hh >= HDIM) continue;
            const unsigned short* row = fp + hh * WDIM;
            union { uint4 q4; unsigned short u[8]; } bA, bB;
            bA.q4 = *reinterpret_cast<const uint4*>(row + wb);
            bB.q4 = *reinterpret_cast<const uint4*>(row + wb + 8);
            float lft = bf2f(row[wb == 0 ? 0 : wb - 1]);
            if (wb == 0)   lft = 0.f;
            float rgt = bf2f(row[wb == 112 ? 127 : wb + 16]);
            if (wb == 112) rgt = 0.f;
            float rv[18];
            rv[0] = lft;
            #pragma unroll
            for (int z = 0; z < 8; ++z) rv[1 + z] = bf2f(bA.u[z]);
            #pragma unroll
            for (int z = 0; z < 8; ++z) rv[9 + z] = bf2f(bB.u[z]);
            rv[17] = rgt;
            float g0 = gv[(dy + 1) * 3], g1 = gv[(dy + 1) * 3 + 1], g2 = gv[(dy + 1) * 3 + 2];
            #pragma unroll
            for (int i = 0; i < 16; ++i)
                y[i] += g0 * rv[i] + g1 * rv[i + 1] + g2 * rv[i + 2];
        }
        union { uint4 q4[2]; unsigned short u[16]; } pk;
        #pragma unroll
        for (int i = 0; i < 16; ++i) pk.u[i] = f2bf(y[i]);
        *reinterpret_cast<uint4*>(&ylds[o][wb])     = pk.q4[0];
        *reinterpret_cast<uint4*>(&ylds[o][wb + 8]) = pk.q4[1];
    }
    __syncthreads();

    int lane = t & 63, wv = t >> 6, gq = lane >> 4, l15 = lane & 15;
    int chb = (wv & 3) * 64, pxb = (wv >> 2) * 64;
    f32x4 acc[4][4];
    #pragma unroll
    for (int a = 0; a < 4; ++a)
        #pragma unroll
        for (int b = 0; b < 4; ++b) acc[a][b] = (f32x4){0.f,0.f,0.f,0.f};

    #pragma unroll
    for (int kc = 0; kc < 2; ++kc) {
        bf16x8 bfr[4];
        #pragma unroll
        for (int pj = 0; pj < 4; ++pj) {
            union { bf16x8 v; unsigned short u[8]; } bb;
            #pragma unroll
            for (int e = 0; e < 8; ++e)
                bb.u[e] = ylds[kc * 32 + gq * 8 + e][pxb + pj * 16 + l15];
            bfr[pj] = bb.v;
        }
        #pragma unroll
        for (int mc = 0; mc < 4; ++mc) {
            int mtile = (wv & 3) * 4 + mc;
            bf16x8 a = *reinterpret_cast<const bf16x8*>(
                fwpk + ((mtile * 2 + kc) * 64 + lane) * 8);
            #pragma unroll
            for (int pj = 0; pj < 4; ++pj)        // SWAPPED: D^T = y^T . w^T
                acc[mc][pj] = __builtin_amdgcn_mfma_f32_16x16x32_bf16(bfr[pj], a, acc[mc][pj], 0, 0, 0);
        }
    }

    // lane holds: c = chb + mc*16 + l15, px = pxb + pj*16 + gq*4 + e
    size_t outbase = (size_t)n * C * HW + (size_t)h * WDIM;
    #pragma unroll
    for (int mc = 0; mc < 4; ++mc) {
        int c = chb + mc * 16 + l15;
        float bias = fbe[c];
        #pragma unroll
        for (int pj = 0; pj < 4; ++pj) {
            int w = pxb + pj * 16 + gq * 4;
            f32x4 vv;
            #pragma unroll
            for (int e = 0; e < 4; ++e) vv[e] = acc[mc][pj][e] + bias;
            *reinterpret_cast<f32x4*>(&out[outbase + (size_t)c * HW + w]) = vv;
        }
    }
}

// ---------------------------------------------------------------------------
extern "C" void kernel_launch(void* const* d_in, const int* in_sizes, int n_in,
                              void* d_out, int out_size, void* d_ws, size_t ws_size,
                              hipStream_t stream) {
    const float* x      = (const float*)d_in[0];
    const float* conv_w = (const float*)d_in[1];
    const float* conv_b = (const float*)d_in[2];
    const float* dw_b   = (const float*)d_in[3];
    const float* fuse_w = (const float*)d_in[4];
    const float* fuse_b = (const float*)d_in[5];
    float* out = (float*)d_out;

    char* ws = (char*)d_ws;
    unsigned short* f_ws = (unsigned short*)ws;                      // 32 MiB
    float* psum          = (float*)(ws + 33554432);                  // 1.57 MiB
    float* gsum          = (float*)(ws + 33554432 + 2097152);        // 36 KiB
    unsigned short* cwpk = (unsigned short*)(ws + 33554432 + 2097152 + 36864);
    unsigned short* fwpk = (unsigned short*)(ws + 33554432 + 2097152 + 36864 + 32768);
    float* fbe           = (float*)(ws + 33554432 + 2097152 + 36864 + 32768 + 32768);

    k0_pack<<<dim3(64), dim3(256), 0, stream>>>(conv_w, fuse_w, fuse_b, dw_b, cwpk, fwpk, fbe);
    k1_conv<<<dim3(1024), dim3(512), 0, stream>>>(x, cwpk, conv_b, f_ws, psum);
    k2_reduce<<<dim3(1024), dim3(128), 0, stream>>>(psum, gsum);
    k3_dwfuse<<<dim3(2048), dim3(512), 0, stream>>>(f_ws, gsum, fwpk, fbe, out);
}